// Round 20
// baseline (81.042 us; speedup 1.0000x reference)
//
#include <hip/hip_runtime.h>

#define S_LEN 4096
#define EMBD  1024
#define HEADD 64

typedef __bf16 bf16x8 __attribute__((ext_vector_type(8)));
typedef float  f32x4  __attribute__((ext_vector_type(4)));

__device__ __forceinline__ unsigned short f2bf(float f) {
  union { float f; unsigned u; } x; x.f = f;
  unsigned r = x.u + 0x7FFFu + ((x.u >> 16) & 1u);
  return (unsigned short)(r >> 16);
}

__device__ __forceinline__ bf16x8 cvt8(f32x4 a, f32x4 b) {
  union { bf16x8 v; unsigned short s[8]; } u;
#pragma unroll
  for (int j = 0; j < 4; j++) { u.s[j] = f2bf(a[j]); u.s[4 + j] = f2bf(b[j]); }
  return u.v;
}

__device__ __forceinline__ unsigned fbits(float f) {
  union { float f; unsigned u; } x; x.f = f; return x.u;
}

// ---------------- Kernel 0: W transpose/convert + bias; fold scale*log2e into Q ----
__global__ void prep_w(const float* __restrict__ Wk, const float* __restrict__ bk,
                       const float* __restrict__ Wq, const float* __restrict__ bq,
                       const float* __restrict__ Wv, const float* __restrict__ bv,
                       unsigned short* __restrict__ wt, float* __restrict__ bias) {
  int n = blockIdx.x;            // 0..191 : [0,64)=K, [64,128)=Q(scaled), [128,192)=V
  int t = threadIdx.x;
  const float QSCALE = 0.125f * 1.44269504088896340736f;  // 1/sqrt(64) * log2(e)
  const float* W; const float* bsrc; int col; float s = 1.0f;
  if (n < 64)       { W = Wk; bsrc = bk; col = n; }
  else if (n < 128) { W = Wq; bsrc = bq; col = n - 64; s = QSCALE; }
  else              { W = Wv; bsrc = bv; col = n - 128; }
  for (int k = t; k < EMBD; k += 256)
    wt[n * EMBD + k] = f2bf(W[k * HEADD + col] * s);
  if (t == 0) bias[n] = bsrc[col] * s;
}

// ---------------- Kernel 1: QKV projection, N-split x2, 2 blocks/CU -----------------
// 512 blocks (256 row-groups x 2 N-halves) x 128 thr (2 waves). Wave keeps the
// measured-best shape: 64 rows x 48 cols = 12 MFMA per 3 W-loads per K-step.
// 2 co-resident blocks/CU: block B computes through block A's stage-waits and
// barriers (TLP instead of the compiler-defeated reg-prefetch ILP). Cost: X is
// staged once per block (2x per CU); second read is L3-absorbed (64MB < 256MB).
// 1 wave/SIMD -> 512 VGPR cap; ~210 live regs fit.
__global__ __launch_bounds__(128, 2) void proj_qkv(
    const float* __restrict__ X, const unsigned short* __restrict__ wt,
    const float* __restrict__ bias,
    unsigned short* __restrict__ qws, unsigned short* __restrict__ kws,
    unsigned short* __restrict__ vtws) {
  __shared__ unsigned short xs[64 * 256];    // 32 KB, XOR-swizzled 16B slots

  const int tid = threadIdx.x;
  const int w = tid >> 6;                    // wave 0..1
  const int lane = tid & 63;
  const int l15 = lane & 15, lg = lane >> 4;
  const int nh = blockIdx.x & 1;             // N-half: cols [nh*96, nh*96+96)
  const int row0 = (blockIdx.x >> 1) * 64;

  const int sr = tid >> 5;                   // stage: 4 rows per iteration
  const int sc = (tid & 31) * 8;             // stage: f32 col

  const unsigned short* wp = wt + (size_t)(nh * 96 + w * 48 + l15) * EMBD + lg * 8;

  f32x4 acc[4][3];
#pragma unroll
  for (int g = 0; g < 4; g++)
#pragma unroll
    for (int j = 0; j < 3; j++) acc[g][j] = (f32x4){0.f, 0.f, 0.f, 0.f};

  f32x4 la[16], lb[16];
#pragma unroll
  for (int it = 0; it < 16; it++) {
    const int r = it * 4 + sr;
    const float* src = X + (size_t)(row0 + r) * EMBD + sc;
    la[it] = *(const f32x4*)src;
    lb[it] = *(const f32x4*)(src + 4);
  }
#pragma unroll
  for (int it = 0; it < 16; it++) {
    const int r = it * 4 + sr;
    int soff = (r << 8) + sc;
    soff ^= (r & 7) << 3;
    *(bf16x8*)&xs[soff] = cvt8(la[it], lb[it]);
  }
  __syncthreads();

#pragma unroll
  for (int kc = 0; kc < 4; kc++) {
    if (kc + 1 < 4) {
#pragma unroll
      for (int it = 0; it < 16; it++) {
        const int r = it * 4 + sr;
        const float* src = X + (size_t)(row0 + r) * EMBD + (kc + 1) * 256 + sc;
        la[it] = *(const f32x4*)src;
        lb[it] = *(const f32x4*)(src + 4);
      }
    }
    bf16x8 wf[2][3];
#pragma unroll
    for (int j = 0; j < 3; j++)
      wf[0][j] = *(const bf16x8*)(wp + (size_t)j * 16 * EMBD + kc * 256);
#pragma unroll
    for (int ss = 0; ss < 8; ss++) {
      const int cur = ss & 1;
      if (ss + 1 < 8) {
#pragma unroll
        for (int j = 0; j < 3; j++)
          wf[cur ^ 1][j] = *(const bf16x8*)(wp + (size_t)j * 16 * EMBD + kc * 256 + (ss + 1) * 32);
      }
      const int c = ss * 32 + lg * 8;
      bf16x8 a[4];
#pragma unroll
      for (int g = 0; g < 4; g++) {
        int so = ((g * 16 + l15) << 8) + c;
        so ^= (l15 & 7) << 3;
        a[g] = *(const bf16x8*)&xs[so];
      }
#pragma unroll
      for (int j = 0; j < 3; j++)
#pragma unroll
        for (int g = 0; g < 4; g++)
          acc[g][j] = __builtin_amdgcn_mfma_f32_16x16x32_bf16(a[g], wf[cur][j], acc[g][j], 0, 0, 0);
    }
    __syncthreads();
    if (kc + 1 < 4) {
#pragma unroll
      for (int it = 0; it < 16; it++) {
        const int r = it * 4 + sr;
        int soff = (r << 8) + sc;
        soff ^= (r & 7) << 3;
        *(bf16x8*)&xs[soff] = cvt8(la[it], lb[it]);
      }
      __syncthreads();
    }
  }

  // ---- epilogue: 4 row-groups x 3 N-frags (this block's N-half) ----
#pragma unroll
  for (int g = 0; g < 4; g++) {
    const int crow0 = row0 + g * 16 + lg * 4;
#pragma unroll
    for (int j = 0; j < 3; j++) {
      const int nf = nh * 6 + w * 3 + j;
      const int n = nf * 16 + l15;
      const float bs = bias[n];
      if (nf < 8) {
        unsigned short* dst = (nf < 4) ? kws : qws;
        const int nn = n & 63;
#pragma unroll
        for (int i = 0; i < 4; i++)
          dst[(size_t)(crow0 + i) * HEADD + nn] = f2bf(acc[g][j][i] + bs);
      } else {
        const int d = n - 128;
        const int bb = crow0 >> 12, sr2 = crow0 & 4095;
        union { unsigned long long pk; unsigned short s[4]; } u;
#pragma unroll
        for (int i = 0; i < 4; i++) u.s[i] = f2bf(acc[g][j][i] + bs);
        *(unsigned long long*)&vtws[((size_t)bb * HEADD + d) * S_LEN + sr2] = u.pk;
      }
    }
  }
}

// ---------------- Kernel 2: flash attention, kv-slice-4 + FUSED H/L panels (R19) ---
__global__ __launch_bounds__(512, 1) void attn(
    const unsigned short* __restrict__ qws,
    const unsigned short* __restrict__ kws,
    const unsigned short* __restrict__ vtws,
    unsigned short* __restrict__ pO,
    float* __restrict__ pmv, float* __restrict__ plv) {
  __shared__ uint4 kvb[2][1024];             // [buf][ K 8KB | V 8KB ] = 32 KB
  __shared__ unsigned short pbl[8][16][72];  // per-wave P bounce (shared H/L)

  const int tid = threadIdx.x;
  const int w = tid >> 6;
  const int lane = tid & 63;
  const int l15 = lane & 15, lg = lane >> 4;
  const int srow = tid >> 3;                 // stage row 0..63
  const int scol = (tid & 7) * 8;            // stage col (elems)
  const int soff = ((srow * 128 + (tid & 7) * 16)) ^ ((srow & 7) << 4);

  const int id = blockIdx.x;
  const int b = id & 3;                      // batch
  const int x = (id >> 2) & 15;              // pair index
  const int h = id >> 6;                     // kv slice 0..3

  const unsigned short* kb = kws + (size_t)b * S_LEN * HEADD;
  const unsigned short* vb = vtws + (size_t)b * HEADD * S_LEN;
  const unsigned short* qp = qws + (size_t)b * S_LEN * HEADD;

  const int PH = 31 - x, PL = x;
  const int tlPH = 2 * PH + 1;               // stage bound (heavy superset)
  const int tlwH = 2 * PH + (w >> 2);        // per-wave diagonal tiles
  const int tlwL = 2 * PL + (w >> 2);
  const int qbH = PH * 128 + w * 16;
  const int qbL = PL * 128 + w * 16;

  const unsigned short* qH = qp + (size_t)(qbH + l15) * HEADD + lg * 8;
  const unsigned short* qL = qp + (size_t)(qbL + l15) * HEADD + lg * 8;
  const bf16x8 bqH0 = *(const bf16x8*)qH, bqH1 = *(const bf16x8*)(qH + 32);
  const bf16x8 bqL0 = *(const bf16x8*)qL, bqL1 = *(const bf16x8*)(qL + 32);

  f32x4 oH[4], oL[4];
#pragma unroll
  for (int nd = 0; nd < 4; nd++) {
    oH[nd] = (f32x4){0.f, 0.f, 0.f, 0.f};
    oL[nd] = (f32x4){0.f, 0.f, 0.f, 0.f};
  }
  float mH = -3.0e38f, lH = 0.f, mL = -3.0e38f, lL = 0.f;

#define PROC(BQ0, BQ1, O, M, LL, QB, TLX, tt, base)                             \
  do {                                                                          \
    bf16x8 k0[4], k1[4], v0[4], v1[4];                                          \
    _Pragma("unroll")                                                           \
    for (int nf = 0; nf < 4; nf++) {                                            \
      const int r = nf * 16 + l15;                                              \
      const int sw = (l15 & 7) << 4;                                            \
      const int b0 = (r * 128 + lg * 16) ^ sw;                                  \
      const int b1 = (r * 128 + 64 + lg * 16) ^ sw;                             \
      k0[nf] = *(const bf16x8*)&base[b0];                                       \
      k1[nf] = *(const bf16x8*)&base[b1];                                       \
      v0[nf] = *(const bf16x8*)&base[8192 + b0];                                \
      v1[nf] = *(const bf16x8*)&base[8192 + b1];                                \
    }                                                                           \
    f32x4 sc[4];                                                                \
    __builtin_amdgcn_s_setprio(1);                                              \
    _Pragma("unroll")                                                           \
    for (int nf = 0; nf < 4; nf++) {                                            \
      f32x4 z = (f32x4){0.f, 0.f, 0.f, 0.f};                                    \
      z = __builtin_amdgcn_mfma_f32_16x16x32_bf16(k0[nf], BQ0, z, 0, 0, 0);     \
      sc[nf] = __builtin_amdgcn_mfma_f32_16x16x32_bf16(k1[nf], BQ1, z, 0, 0, 0);\
    }                                                                           \
    __builtin_amdgcn_s_setprio(0);                                              \
    if ((tt) == (TLX)) {                                                        \
      const int qa = (QB) + l15;                                                \
      _Pragma("unroll")                                                         \
      for (int nf = 0; nf < 4; nf++)                                            \
        _Pragma("unroll")                                                       \
        for (int i = 0; i < 4; i++)                                             \
          if ((tt) * 64 + nf * 16 + lg * 4 + i > qa) sc[nf][i] = -1.0e30f;      \
    }                                                                           \
    float pm = sc[0][0];                                                        \
    _Pragma("unroll")                                                           \
    for (int nf = 0; nf < 4; nf++)                                              \
      _Pragma("unroll")                                                         \
      for (int i = 0; i < 4; i++) pm = fmaxf(pm, sc[nf][i]);                    \
    if (!__all(pm <= M + 8.0f)) {                                               \
      float mx = fmaxf(pm, __shfl_xor(pm, 16));                                 \
      mx = fmaxf(mx, __shfl_xor(mx, 32));                                       \
      const float mn = fmaxf(M, mx);                                            \
      const float al = __builtin_amdgcn_exp2f(M - mn);                          \
      M = mn;                                                                   \
      LL *= al;                                                                 \
      float alr[4];                                                             \
      _Pragma("unroll")                                                         \
      for (int i = 0; i < 4; i++) alr[i] = __shfl(al, lg * 4 + i);              \
      _Pragma("unroll")                                                         \
      for (int nd = 0; nd < 4; nd++)                                            \
        _Pragma("unroll")                                                       \
        for (int i = 0; i < 4; i++) O[nd][i] *= alr[i];                         \
    }                                                                           \
    _Pragma("unroll")                                                           \
    for (int nf = 0; nf < 4; nf++) {                                            \
      f32x4 p;                                                                  \
      _Pragma("unroll")                                                         \
      for (int i = 0; i < 4; i++) p[i] = __builtin_amdgcn_exp2f(sc[nf][i] - M); \
      LL += p[0] + p[1] + p[2] + p[3];                                          \
      unsigned lo_ = __builtin_amdgcn_perm(fbits(p[1]) + 0x8000u,               \
                                           fbits(p[0]) + 0x8000u, 0x07060302u); \
      unsigned hi_ = __builtin_amdgcn_perm(fbits(p[3]) + 0x8000u,               \
                                           fbits(p[2]) + 0x8000u, 0x07060302u); \
      uint2 pk_; pk_.x = lo_; pk_.y = hi_;                                      \
      *(uint2*)&pbl[w][l15][nf * 16 + lg * 4] = pk_;                            \
    }                                                                           \
    const bf16x8 ap0 = *(const bf16x8*)&pbl[w][l15][lg * 8];                    \
    const bf16x8 ap1 = *(const bf16x8*)&pbl[w][l15][32 + lg * 8];               \
    __builtin_amdgcn_s_setprio(1);                                              \
    _Pragma("unroll")                                                           \
    for (int nd = 0; nd < 4; nd++) {                                            \
      f32x4 oo = __builtin_amdgcn_mfma_f32_16x16x32_bf16(ap0, v0[nd], O[nd], 0, 0, 0); \
      O[nd] = __builtin_amdgcn_mfma_f32_16x16x32_bf16(ap1, v1[nd], oo, 0, 0, 0);\
    }                                                                           \
    __builtin_amdgcn_s_setprio(0);                                              \
  } while (0)

#define LOADG(tt)                                                               \
  do {                                                                          \
    kreg = *(const uint4*)(kb + ((size_t)(tt) * 64 + srow) * HEADD + scol);     \
    vreg = *(const uint4*)(vb + (size_t)srow * S_LEN + (tt) * 64 + scol);       \
  } while (0)

#define WRITEL(bf)                                                              \
  do {                                                                          \
    unsigned char* d_ = (unsigned char*)kvb[bf];                                \
    *(uint4*)&d_[soff] = kreg;                                                  \
    *(uint4*)&d_[8192 + soff] = vreg;                                           \
  } while (0)

  // ---- single fused pass over the heavy panel's tile sequence (stride 4) ----
  {
    uint4 kreg, vreg;
    int t = h;                               // h <= 3 <= tlPH (>= 33) always
    LOADG(t);
    WRITEL(0);
    __syncthreads();
    int cur = 0;
#pragma unroll 1
    while (true) {
      const int tn = t + 4;
      const bool hn = tn <= tlPH;
      if (hn) LOADG(tn);                     // in flight during compute (T14)
      {
        const unsigned char* base = (const unsigned char*)kvb[cur];
        if (t <= tlwH) PROC(bqH0, bqH1, oH, mH, lH, qbH, tlwH, t, base);
        if (t <= tlwL) PROC(bqL0, bqL1, oL, mL, lL, qbL, tlwL, t, base);
      }
      if (!hn) break;
      WRITEL(cur ^ 1);                       // vmcnt waits here, after compute
      __syncthreads();                       // one barrier per tile
      cur ^= 1;
      t = tn;
    }
  }

  // ---- per-wave partials for BOTH groups -> ws ----
  lH += __shfl_xor(lH, 16);
  lH += __shfl_xor(lH, 32);
  lL += __shfl_xor(lL, 16);
  lL += __shfl_xor(lL, 32);
  const size_t pbH = (size_t)(h * 4 + b) * S_LEN + qbH;
  const size_t pbL = (size_t)(h * 4 + b) * S_LEN + qbL;
  if (lane < 16) {
    pmv[pbH + lane] = mH; plv[pbH + lane] = lH;
    pmv[pbL + lane] = mL; plv[pbL + lane] = lL;
  }
#pragma unroll
  for (int nd = 0; nd < 4; nd++)
#pragma unroll
    for (int i = 0; i < 4; i++) {
      pO[(pbH + lg * 4 + i) * 64 + nd * 16 + l15] = f2bf(oH[nd][i]);
      pO[(pbL + lg * 4 + i) * 64 + nd * 16 + l15] = f2bf(oL[nd][i]);
    }
#undef PROC
#undef LOADG
#undef WRITEL
}

// ---------------- Kernel 3: merge the 4 kv-slices ----------------------------------
__global__ __launch_bounds__(256) void merge_attn(
    const unsigned short* __restrict__ pO,
    const float* __restrict__ pmv, const float* __restrict__ plv,
    float* __restrict__ out) {
  const int row = blockIdx.x * 64 + (threadIdx.x >> 2);  // 0..16383 (= b*4096+r)
  const int q = threadIdx.x & 3;
  float mh[4], lh[4];
  float M = -3.0e38f;
#pragma unroll
  for (int hh = 0; hh < 4; hh++) {
    mh[hh] = pmv[hh * 16384 + row];
    lh[hh] = plv[hh * 16384 + row];
    M = fmaxf(M, mh[hh]);
  }
  float Lt = 0.f, a[4];
#pragma unroll
  for (int hh = 0; hh < 4; hh++) {
    a[hh] = __builtin_amdgcn_exp2f(mh[hh] - M);
    Lt += a[hh] * lh[hh];
  }
  const float iL = 1.0f / Lt;
  float acc[16];
#pragma unroll
  for (int c = 0; c < 16; c++) acc[c] = 0.f;
#pragma unroll
  for (int hh = 0; hh < 4; hh++) {
    const unsigned short* src = pO + ((size_t)hh * 16384 + row) * 64 + q * 16;
    const uint4 u0 = *(const uint4*)(src);
    const uint4 u1 = *(const uint4*)(src + 8);
    const unsigned* uu0 = (const unsigned*)&u0;
    const unsigned* uu1 = (const unsigned*)&u1;
#pragma unroll
    for (int j = 0; j < 4; j++) {
      union { unsigned u; float f; } e0, e1, e2, e3;
      e0.u = uu0[j] << 16;  e1.u = uu0[j] & 0xffff0000u;
      e2.u = uu1[j] << 16;  e3.u = uu1[j] & 0xffff0000u;
      acc[j * 2 + 0] += e0.f * a[hh];
      acc[j * 2 + 1] += e1.f * a[hh];
      acc[8 + j * 2 + 0] += e2.f * a[hh];
      acc[8 + j * 2 + 1] += e3.f * a[hh];
    }
  }
  float* dst = out + (size_t)row * 64 + q * 16;
#pragma unroll
  for (int c = 0; c < 16; c++) dst[c] = acc[c] * iL;
}

extern "C" void kernel_launch(void* const* d_in, const int* in_sizes, int n_in,
                              void* d_out, int out_size, void* d_ws, size_t ws_size,
                              hipStream_t stream) {
  const float* X  = (const float*)d_in[0];
  const float* Wk = (const float*)d_in[1];
  const float* bk = (const float*)d_in[2];
  const float* Wq = (const float*)d_in[3];
  const float* bq = (const float*)d_in[4];
  const float* Wv = (const float*)d_in[5];
  const float* bv = (const float*)d_in[6];
  float* out = (float*)d_out;

  char* ws = (char*)d_ws;
  unsigned short* kws  = (unsigned short*)(ws);                      // 2 MB
  unsigned short* qws  = (unsigned short*)(ws + (2u << 20));         // 2 MB
  unsigned short* vtws = (unsigned short*)(ws + (4u << 20));         // 2 MB (transposed)
  unsigned short* wt   = (unsigned short*)(ws + (6u << 20));         // 384 KB
  float*          bias = (float*)(ws + (6u << 20) + (512u << 10));   // 768 B
  unsigned short* pO   = (unsigned short*)(ws + (8u << 20));         // 8 MB bf16
  float*          pmv  = (float*)(ws + (16u << 20));                 // 256 KB
  float*          plv  = (float*)(ws + (17u << 20));                 // 256 KB

  prep_w<<<dim3(192), dim3(256), 0, stream>>>(Wk, bk, Wq, bq, Wv, bv, wt, bias);
  proj_qkv<<<dim3(512), dim3(128), 0, stream>>>(X, wt, bias, qws, kws, vtws);
  attn<<<dim3(256), dim3(512), 0, stream>>>(qws, kws, vtws, pO, pmv, plv);
  merge_attn<<<dim3(256), dim3(256), 0, stream>>>(pO, pmv, plv, out);
}

// Round 21
// 60.938 us; speedup vs baseline: 1.3299x; 1.3299x over previous
//
#include <hip/hip_runtime.h>

#define S_LEN 4096
#define EMBD  1024
#define HEADD 64

typedef __bf16 bf16x8 __attribute__((ext_vector_type(8)));
typedef float  f32x4  __attribute__((ext_vector_type(4)));

__device__ __forceinline__ unsigned short f2bf(float f) {
  union { float f; unsigned u; } x; x.f = f;
  unsigned r = x.u + 0x7FFFu + ((x.u >> 16) & 1u);
  return (unsigned short)(r >> 16);
}

__device__ __forceinline__ bf16x8 cvt8(f32x4 a, f32x4 b) {
  union { bf16x8 v; unsigned short s[8]; } u;
#pragma unroll
  for (int j = 0; j < 4; j++) { u.s[j] = f2bf(a[j]); u.s[4 + j] = f2bf(b[j]); }
  return u.v;
}

__device__ __forceinline__ unsigned fbits(float f) {
  union { float f; unsigned u; } x; x.f = f; return x.u;
}

// ---------------- Kernel 0: W transpose/convert + bias; fold scale*log2e into Q ----
__global__ void prep_w(const float* __restrict__ Wk, const float* __restrict__ bk,
                       const float* __restrict__ Wq, const float* __restrict__ bq,
                       const float* __restrict__ Wv, const float* __restrict__ bv,
                       unsigned short* __restrict__ wt, float* __restrict__ bias) {
  int n = blockIdx.x;            // 0..191 : [0,64)=K, [64,128)=Q(scaled), [128,192)=V
  int t = threadIdx.x;
  const float QSCALE = 0.125f * 1.44269504088896340736f;  // 1/sqrt(64) * log2(e)
  const float* W; const float* bsrc; int col; float s = 1.0f;
  if (n < 64)       { W = Wk; bsrc = bk; col = n; }
  else if (n < 128) { W = Wq; bsrc = bq; col = n - 64; s = QSCALE; }
  else              { W = Wv; bsrc = bv; col = n - 128; }
  for (int k = t; k < EMBD; k += 256)
    wt[n * EMBD + k] = f2bf(W[k * HEADD + col] * s);
  if (t == 0) bias[n] = bsrc[col] * s;
}

// ---------------- Kernel 1: QKV projection, R11 structure with BK=512 ---------------
// 256 blocks (1/CU) x 256 thr (4 waves). Wave = 64 rows x 48 cols (12 MFMA per
// 3 W-loads/K-step — the only measured-good shape). BK=512: 2 chunks instead of
// 4 -> half the full-CU barrier+drain stalls. 64 KB LDS single logical buffer;
// prefetch la/lb[16] (128 VGPRs) lives under the 512 cap at 1 wave/SIMD.
// Measured-dead alternatives (do not revisit): 32-row blocks (R14), f32
// global_load_lds (R17/R18), N-split 2 blocks/CU (R20).
__global__ __launch_bounds__(256, 1) void proj_qkv(
    const float* __restrict__ X, const unsigned short* __restrict__ wt,
    const float* __restrict__ bias,
    unsigned short* __restrict__ qws, unsigned short* __restrict__ kws,
    unsigned short* __restrict__ vtws) {
  __shared__ unsigned short xs[64 * 512];    // 64 KB, XOR-swizzled 16B slots

  const int tid = threadIdx.x;
  const int w = tid >> 6;                    // wave = N-slice (48 cols)
  const int lane = tid & 63;
  const int l15 = lane & 15, lg = lane >> 4;
  const int row0 = blockIdx.x * 64;

  const int sr = tid >> 5;                   // stage row stride 8
  const int sc = (tid & 31) * 8;             // stage col (f32), stride 256/row-pass

  const unsigned short* wp = wt + (size_t)(w * 48 + l15) * EMBD + lg * 8;

  f32x4 acc[4][3];
#pragma unroll
  for (int g = 0; g < 4; g++)
#pragma unroll
    for (int j = 0; j < 3; j++) acc[g][j] = (f32x4){0.f, 0.f, 0.f, 0.f};

  // prefetch buffers for one 512-col chunk: 16 iterations of (8 rows x 256 cols)
  f32x4 la[16], lb[16];
#pragma unroll
  for (int it = 0; it < 16; it++) {
    const int r = (it & 7) * 8 + sr;
    const int c = (it >> 3) * 256 + sc;
    const float* src = X + (size_t)(row0 + r) * EMBD + c;
    la[it] = *(const f32x4*)src;
    lb[it] = *(const f32x4*)(src + 4);
  }
#pragma unroll
  for (int it = 0; it < 16; it++) {
    const int r = (it & 7) * 8 + sr;
    const int c = (it >> 3) * 256 + sc;
    int soff = (r << 9) + c;
    soff ^= (r & 7) << 3;                    // 16B-slot XOR swizzle
    *(bf16x8*)&xs[soff] = cvt8(la[it], lb[it]);
  }
  __syncthreads();

#pragma unroll
  for (int kc = 0; kc < 2; kc++) {
    if (kc + 1 < 2) {
#pragma unroll
      for (int it = 0; it < 16; it++) {
        const int r = (it & 7) * 8 + sr;
        const int c = 512 + (it >> 3) * 256 + sc;
        const float* src = X + (size_t)(row0 + r) * EMBD + c;
        la[it] = *(const f32x4*)src;
        lb[it] = *(const f32x4*)(src + 4);
      }
    }
    bf16x8 wf[2][3];
#pragma unroll
    for (int j = 0; j < 3; j++)
      wf[0][j] = *(const bf16x8*)(wp + (size_t)j * 16 * EMBD + kc * 512);
#pragma unroll
    for (int ss = 0; ss < 16; ss++) {
      const int cur = ss & 1;
      if (ss + 1 < 16) {
#pragma unroll
        for (int j = 0; j < 3; j++)
          wf[cur ^ 1][j] = *(const bf16x8*)(wp + (size_t)j * 16 * EMBD + kc * 512 + (ss + 1) * 32);
      }
      const int c = ss * 32 + lg * 8;
      bf16x8 a[4];
#pragma unroll
      for (int g = 0; g < 4; g++) {
        int so = ((g * 16 + l15) << 9) + c;
        so ^= (l15 & 7) << 3;
        a[g] = *(const bf16x8*)&xs[so];
      }
#pragma unroll
      for (int j = 0; j < 3; j++)
#pragma unroll
        for (int g = 0; g < 4; g++)
          acc[g][j] = __builtin_amdgcn_mfma_f32_16x16x32_bf16(a[g], wf[cur][j], acc[g][j], 0, 0, 0);
    }
    __syncthreads();
    if (kc + 1 < 2) {
#pragma unroll
      for (int it = 0; it < 16; it++) {
        const int r = (it & 7) * 8 + sr;
        const int c = (it >> 3) * 256 + sc;
        int soff = (r << 9) + c;
        soff ^= (r & 7) << 3;
        *(bf16x8*)&xs[soff] = cvt8(la[it], lb[it]);
      }
      __syncthreads();
    }
  }

  // ---- epilogue: 4 row-groups x 3 N-frags ----
#pragma unroll
  for (int g = 0; g < 4; g++) {
    const int crow0 = row0 + g * 16 + lg * 4;
#pragma unroll
    for (int j = 0; j < 3; j++) {
      const int nf = w * 3 + j;
      const int n = nf * 16 + l15;
      const float bs = bias[n];
      if (nf < 8) {
        unsigned short* dst = (nf < 4) ? kws : qws;
        const int nn = n & 63;
#pragma unroll
        for (int i = 0; i < 4; i++)
          dst[(size_t)(crow0 + i) * HEADD + nn] = f2bf(acc[g][j][i] + bs);
      } else {
        const int d = n - 128;
        const int bb = crow0 >> 12, sr2 = crow0 & 4095;
        union { unsigned long long pk; unsigned short s[4]; } u;
#pragma unroll
        for (int i = 0; i < 4; i++) u.s[i] = f2bf(acc[g][j][i] + bs);
        *(unsigned long long*)&vtws[((size_t)bb * HEADD + d) * S_LEN + sr2] = u.pk;
      }
    }
  }
}

// ---------------- Kernel 2: flash attention, kv-slice-4 + FUSED H/L panels (R19) ---
__global__ __launch_bounds__(512, 1) void attn(
    const unsigned short* __restrict__ qws,
    const unsigned short* __restrict__ kws,
    const unsigned short* __restrict__ vtws,
    unsigned short* __restrict__ pO,
    float* __restrict__ pmv, float* __restrict__ plv) {
  __shared__ uint4 kvb[2][1024];             // [buf][ K 8KB | V 8KB ] = 32 KB
  __shared__ unsigned short pbl[8][16][72];  // per-wave P bounce (shared H/L)

  const int tid = threadIdx.x;
  const int w = tid >> 6;
  const int lane = tid & 63;
  const int l15 = lane & 15, lg = lane >> 4;
  const int srow = tid >> 3;                 // stage row 0..63
  const int scol = (tid & 7) * 8;            // stage col (elems)
  const int soff = ((srow * 128 + (tid & 7) * 16)) ^ ((srow & 7) << 4);

  const int id = blockIdx.x;
  const int b = id & 3;                      // batch
  const int x = (id >> 2) & 15;              // pair index
  const int h = id >> 6;                     // kv slice 0..3

  const unsigned short* kb = kws + (size_t)b * S_LEN * HEADD;
  const unsigned short* vb = vtws + (size_t)b * HEADD * S_LEN;
  const unsigned short* qp = qws + (size_t)b * S_LEN * HEADD;

  const int PH = 31 - x, PL = x;
  const int tlPH = 2 * PH + 1;               // stage bound (heavy superset)
  const int tlwH = 2 * PH + (w >> 2);        // per-wave diagonal tiles
  const int tlwL = 2 * PL + (w >> 2);
  const int qbH = PH * 128 + w * 16;
  const int qbL = PL * 128 + w * 16;

  const unsigned short* qH = qp + (size_t)(qbH + l15) * HEADD + lg * 8;
  const unsigned short* qL = qp + (size_t)(qbL + l15) * HEADD + lg * 8;
  const bf16x8 bqH0 = *(const bf16x8*)qH, bqH1 = *(const bf16x8*)(qH + 32);
  const bf16x8 bqL0 = *(const bf16x8*)qL, bqL1 = *(const bf16x8*)(qL + 32);

  f32x4 oH[4], oL[4];
#pragma unroll
  for (int nd = 0; nd < 4; nd++) {
    oH[nd] = (f32x4){0.f, 0.f, 0.f, 0.f};
    oL[nd] = (f32x4){0.f, 0.f, 0.f, 0.f};
  }
  float mH = -3.0e38f, lH = 0.f, mL = -3.0e38f, lL = 0.f;

#define PROC(BQ0, BQ1, O, M, LL, QB, TLX, tt, base)                             \
  do {                                                                          \
    bf16x8 k0[4], k1[4], v0[4], v1[4];                                          \
    _Pragma("unroll")                                                           \
    for (int nf = 0; nf < 4; nf++) {                                            \
      const int r = nf * 16 + l15;                                              \
      const int sw = (l15 & 7) << 4;                                            \
      const int b0 = (r * 128 + lg * 16) ^ sw;                                  \
      const int b1 = (r * 128 + 64 + lg * 16) ^ sw;                             \
      k0[nf] = *(const bf16x8*)&base[b0];                                       \
      k1[nf] = *(const bf16x8*)&base[b1];                                       \
      v0[nf] = *(const bf16x8*)&base[8192 + b0];                                \
      v1[nf] = *(const bf16x8*)&base[8192 + b1];                                \
    }                                                                           \
    f32x4 sc[4];                                                                \
    __builtin_amdgcn_s_setprio(1);                                              \
    _Pragma("unroll")                                                           \
    for (int nf = 0; nf < 4; nf++) {                                            \
      f32x4 z = (f32x4){0.f, 0.f, 0.f, 0.f};                                    \
      z = __builtin_amdgcn_mfma_f32_16x16x32_bf16(k0[nf], BQ0, z, 0, 0, 0);     \
      sc[nf] = __builtin_amdgcn_mfma_f32_16x16x32_bf16(k1[nf], BQ1, z, 0, 0, 0);\
    }                                                                           \
    __builtin_amdgcn_s_setprio(0);                                              \
    if ((tt) == (TLX)) {                                                        \
      const int qa = (QB) + l15;                                                \
      _Pragma("unroll")                                                         \
      for (int nf = 0; nf < 4; nf++)                                            \
        _Pragma("unroll")                                                       \
        for (int i = 0; i < 4; i++)                                             \
          if ((tt) * 64 + nf * 16 + lg * 4 + i > qa) sc[nf][i] = -1.0e30f;      \
    }                                                                           \
    float pm = sc[0][0];                                                        \
    _Pragma("unroll")                                                           \
    for (int nf = 0; nf < 4; nf++)                                              \
      _Pragma("unroll")                                                         \
      for (int i = 0; i < 4; i++) pm = fmaxf(pm, sc[nf][i]);                    \
    if (!__all(pm <= M + 8.0f)) {                                               \
      float mx = fmaxf(pm, __shfl_xor(pm, 16));                                 \
      mx = fmaxf(mx, __shfl_xor(mx, 32));                                       \
      const float mn = fmaxf(M, mx);                                            \
      const float al = __builtin_amdgcn_exp2f(M - mn);                          \
      M = mn;                                                                   \
      LL *= al;                                                                 \
      float alr[4];                                                             \
      _Pragma("unroll")                                                         \
      for (int i = 0; i < 4; i++) alr[i] = __shfl(al, lg * 4 + i);              \
      _Pragma("unroll")                                                         \
      for (int nd = 0; nd < 4; nd++)                                            \
        _Pragma("unroll")                                                       \
        for (int i = 0; i < 4; i++) O[nd][i] *= alr[i];                         \
    }                                                                           \
    _Pragma("unroll")                                                           \
    for (int nf = 0; nf < 4; nf++) {                                            \
      f32x4 p;                                                                  \
      _Pragma("unroll")                                                         \
      for (int i = 0; i < 4; i++) p[i] = __builtin_amdgcn_exp2f(sc[nf][i] - M); \
      LL += p[0] + p[1] + p[2] + p[3];                                          \
      unsigned lo_ = __builtin_amdgcn_perm(fbits(p[1]) + 0x8000u,               \
                                           fbits(p[0]) + 0x8000u, 0x07060302u); \
      unsigned hi_ = __builtin_amdgcn_perm(fbits(p[3]) + 0x8000u,               \
                                           fbits(p[2]) + 0x8000u, 0x07060302u); \
      uint2 pk_; pk_.x = lo_; pk_.y = hi_;                                      \
      *(uint2*)&pbl[w][l15][nf * 16 + lg * 4] = pk_;                            \
    }                                                                           \
    const bf16x8 ap0 = *(const bf16x8*)&pbl[w][l15][lg * 8];                    \
    const bf16x8 ap1 = *(const bf16x8*)&pbl[w][l15][32 + lg * 8];               \
    __builtin_amdgcn_s_setprio(1);                                              \
    _Pragma("unroll")                                                           \
    for (int nd = 0; nd < 4; nd++) {                                            \
      f32x4 oo = __builtin_amdgcn_mfma_f32_16x16x32_bf16(ap0, v0[nd], O[nd], 0, 0, 0); \
      O[nd] = __builtin_amdgcn_mfma_f32_16x16x32_bf16(ap1, v1[nd], oo, 0, 0, 0);\
    }                                                                           \
    __builtin_amdgcn_s_setprio(0);                                              \
  } while (0)

#define LOADG(tt)                                                               \
  do {                                                                          \
    kreg = *(const uint4*)(kb + ((size_t)(tt) * 64 + srow) * HEADD + scol);     \
    vreg = *(const uint4*)(vb + (size_t)srow * S_LEN + (tt) * 64 + scol);       \
  } while (0)

#define WRITEL(bf)                                                              \
  do {                                                                          \
    unsigned char* d_ = (unsigned char*)kvb[bf];                                \
    *(uint4*)&d_[soff] = kreg;                                                  \
    *(uint4*)&d_[8192 + soff] = vreg;                                           \
  } while (0)

  // ---- single fused pass over the heavy panel's tile sequence (stride 4) ----
  {
    uint4 kreg, vreg;
    int t = h;                               // h <= 3 <= tlPH (>= 33) always
    LOADG(t);
    WRITEL(0);
    __syncthreads();
    int cur = 0;
#pragma unroll 1
    while (true) {
      const int tn = t + 4;
      const bool hn = tn <= tlPH;
      if (hn) LOADG(tn);                     // in flight during compute (T14)
      {
        const unsigned char* base = (const unsigned char*)kvb[cur];
        if (t <= tlwH) PROC(bqH0, bqH1, oH, mH, lH, qbH, tlwH, t, base);
        if (t <= tlwL) PROC(bqL0, bqL1, oL, mL, lL, qbL, tlwL, t, base);
      }
      if (!hn) break;
      WRITEL(cur ^ 1);                       // vmcnt waits here, after compute
      __syncthreads();                       // one barrier per tile
      cur ^= 1;
      t = tn;
    }
  }

  // ---- per-wave partials for BOTH groups -> ws ----
  lH += __shfl_xor(lH, 16);
  lH += __shfl_xor(lH, 32);
  lL += __shfl_xor(lL, 16);
  lL += __shfl_xor(lL, 32);
  const size_t pbH = (size_t)(h * 4 + b) * S_LEN + qbH;
  const size_t pbL = (size_t)(h * 4 + b) * S_LEN + qbL;
  if (lane < 16) {
    pmv[pbH + lane] = mH; plv[pbH + lane] = lH;
    pmv[pbL + lane] = mL; plv[pbL + lane] = lL;
  }
#pragma unroll
  for (int nd = 0; nd < 4; nd++)
#pragma unroll
    for (int i = 0; i < 4; i++) {
      pO[(pbH + lg * 4 + i) * 64 + nd * 16 + l15] = f2bf(oH[nd][i]);
      pO[(pbL + lg * 4 + i) * 64 + nd * 16 + l15] = f2bf(oL[nd][i]);
    }
#undef PROC
#undef LOADG
#undef WRITEL
}

// ---------------- Kernel 3: merge the 4 kv-slices ----------------------------------
__global__ __launch_bounds__(256) void merge_attn(
    const unsigned short* __restrict__ pO,
    const float* __restrict__ pmv, const float* __restrict__ plv,
    float* __restrict__ out) {
  const int row = blockIdx.x * 64 + (threadIdx.x >> 2);  // 0..16383 (= b*4096+r)
  const int q = threadIdx.x & 3;
  float mh[4], lh[4];
  float M = -3.0e38f;
#pragma unroll
  for (int hh = 0; hh < 4; hh++) {
    mh[hh] = pmv[hh * 16384 + row];
    lh[hh] = plv[hh * 16384 + row];
    M = fmaxf(M, mh[hh]);
  }
  float Lt = 0.f, a[4];
#pragma unroll
  for (int hh = 0; hh < 4; hh++) {
    a[hh] = __builtin_amdgcn_exp2f(mh[hh] - M);
    Lt += a[hh] * lh[hh];
  }
  const float iL = 1.0f / Lt;
  float acc[16];
#pragma unroll
  for (int c = 0; c < 16; c++) acc[c] = 0.f;
#pragma unroll
  for (int hh = 0; hh < 4; hh++) {
    const unsigned short* src = pO + ((size_t)hh * 16384 + row) * 64 + q * 16;
    const uint4 u0 = *(const uint4*)(src);
    const uint4 u1 = *(const uint4*)(src + 8);
    const unsigned* uu0 = (const unsigned*)&u0;
    const unsigned* uu1 = (const unsigned*)&u1;
#pragma unroll
    for (int j = 0; j < 4; j++) {
      union { unsigned u; float f; } e0, e1, e2, e3;
      e0.u = uu0[j] << 16;  e1.u = uu0[j] & 0xffff0000u;
      e2.u = uu1[j] << 16;  e3.u = uu1[j] & 0xffff0000u;
      acc[j * 2 + 0] += e0.f * a[hh];
      acc[j * 2 + 1] += e1.f * a[hh];
      acc[8 + j * 2 + 0] += e2.f * a[hh];
      acc[8 + j * 2 + 1] += e3.f * a[hh];
    }
  }
  float* dst = out + (size_t)row * 64 + q * 16;
#pragma unroll
  for (int c = 0; c < 16; c++) dst[c] = acc[c] * iL;
}

extern "C" void kernel_launch(void* const* d_in, const int* in_sizes, int n_in,
                              void* d_out, int out_size, void* d_ws, size_t ws_size,
                              hipStream_t stream) {
  const float* X  = (const float*)d_in[0];
  const float* Wk = (const float*)d_in[1];
  const float* bk = (const float*)d_in[2];
  const float* Wq = (const float*)d_in[3];
  const float* bq = (const float*)d_in[4];
  const float* Wv = (const float*)d_in[5];
  const float* bv = (const float*)d_in[6];
  float* out = (float*)d_out;

  char* ws = (char*)d_ws;
  unsigned short* kws  = (unsigned short*)(ws);                      // 2 MB
  unsigned short* qws  = (unsigned short*)(ws + (2u << 20));         // 2 MB
  unsigned short* vtws = (unsigned short*)(ws + (4u << 20));         // 2 MB (transposed)
  unsigned short* wt   = (unsigned short*)(ws + (6u << 20));         // 384 KB
  float*          bias = (float*)(ws + (6u << 20) + (512u << 10));   // 768 B
  unsigned short* pO   = (unsigned short*)(ws + (8u << 20));         // 8 MB bf16
  float*          pmv  = (float*)(ws + (16u << 20));                 // 256 KB
  float*          plv  = (float*)(ws + (17u << 20));                 // 256 KB

  prep_w<<<dim3(192), dim3(256), 0, stream>>>(Wk, bk, Wq, bq, Wv, bv, wt, bias);
  proj_qkv<<<dim3(256), dim3(256), 0, stream>>>(X, wt, bias, qws, kws, vtws);
  attn<<<dim3(256), dim3(512), 0, stream>>>(qws, kws, vtws, pO, pmv, plv);
  merge_attn<<<dim3(256), dim3(256), 0, stream>>>(pO, pmv, plv, out);
}